// Round 1
// baseline (898.823 us; speedup 1.0000x reference)
//
#include <hip/hip_runtime.h>
#include <math.h>

// ---------------------------------------------------------------------------
// MLMPairwiseAtomicEmbedding
// Feature layout per edge (452 f32):
//   [0]       noised_dst
//   [1]       noised_src
//   [2:23]    one_hot(seq[src],21) * !noised_src
//   [23:44]   one_hot(seq[dst],21) * !noised_dst
//   [44:108]  rbf(|Xca[dst]-Xca[src]|), 64
//   [108:172] pos embed: cos(d*freq[0:32]), sin(d*freq[0:32])
//   [172:214] local[src] (42) * !noised_src
//   [214:256] dst_in_src_local (42) * !noised_dst
//   [256:452] pair norms (14x14) * unnoised_edges[-1]  (scalar! last edge)
// ---------------------------------------------------------------------------

#define SCALE 0.1f
#define FEAT 452
// ln(10000)/64 (as f32 of the double), matching exp(arange(0,64,2) * -ln(1e4)/64)
#define POSC64 (-0.14391157f)

__global__ void node_kernel(const float* __restrict__ atom14,
                            const float* __restrict__ rot,
                            const float* __restrict__ trans,
                            const int* __restrict__ mask,
                            float* __restrict__ xca,
                            float* __restrict__ locl,
                            float* __restrict__ eff,
                            int n_nodes) {
    int idx = blockIdx.x * blockDim.x + threadIdx.x;
    int total = n_nodes * 14;
    if (idx >= total) return;
    int n = idx / 14;
    int a = idx - n * 14;

    const float* R = rot + (size_t)n * 9;
    float tx = trans[n * 3 + 0], ty = trans[n * 3 + 1], tz = trans[n * 3 + 2];
    float px = atom14[(size_t)idx * 3 + 0] * SCALE;
    float py = atom14[(size_t)idx * 3 + 1] * SCALE;
    float pz = atom14[(size_t)idx * 3 + 2] * SCALE;

    if (a == 1) {  // X_ca taken from scaled atoms BEFORE the noising replace
        xca[n * 3 + 0] = px;
        xca[n * 3 + 1] = py;
        xca[n * 3 + 2] = pz;
    }

    float ex = px, ey = py, ez = pz;
    if (mask[n] != 0) {
        if (a < 4) {
            // BB_LOCAL rows (z component is 0 for all 4)
            const float BBX[4] = {-0.525f, 0.0f, 1.526f, 2.153f};
            const float BBY[4] = {1.363f, 0.0f, 0.0f, -1.062f};
            float lx = BBX[a], ly = BBY[a];
            // bb[i] = sum_j R[i][j] * L[j] + t[i]   (BB_MASK=1 for a<4)
            ex = R[0] * lx + R[1] * ly + tx;
            ey = R[3] * lx + R[4] * ly + ty;
            ez = R[6] * lx + R[7] * ly + tz;
        } else {
            ex = 0.f; ey = 0.f; ez = 0.f;  // (bb+t)*BB_MASK with mask 0
        }
    }

    // local[a][i] = sum_j R[j][i] * (eff[a][j] - t[j])   (R^T applied)
    float dx = ex - tx, dy = ey - ty, dz = ez - tz;
    float l0 = R[0] * dx + R[3] * dy + R[6] * dz;
    float l1 = R[1] * dx + R[4] * dy + R[7] * dz;
    float l2 = R[2] * dx + R[5] * dy + R[8] * dz;

    eff[(size_t)idx * 3 + 0] = ex;
    eff[(size_t)idx * 3 + 1] = ey;
    eff[(size_t)idx * 3 + 2] = ez;
    locl[(size_t)idx * 3 + 0] = l0;
    locl[(size_t)idx * 3 + 1] = l1;
    locl[(size_t)idx * 3 + 2] = l2;
}

__global__ __launch_bounds__(256) void edge_kernel(
    const int* __restrict__ ei,     // [2,E] row0=dst row1=src
    const int* __restrict__ mask,   // [N]
    const int* __restrict__ seq,    // [N]
    const float* __restrict__ rot,  // [N,3,3]
    const float* __restrict__ trans,// [N,3]
    const float* __restrict__ xca,  // [N,3]
    const float* __restrict__ locl, // [N,14,3]
    const float* __restrict__ eff,  // [N,14,3]
    float* __restrict__ out,        // [E,452]
    int E) {
    __shared__ float la[4][42];  // local[src]
    __shared__ float lb[4][42];  // dst atoms in src frame

    int wid = threadIdx.x >> 6;
    int lane = threadIdx.x & 63;
    int e = blockIdx.x * 4 + wid;
    int ec = (e < E) ? e : (E - 1);

    int dst = ei[ec];
    int src = ei[E + ec];
    bool mdst = mask[dst] != 0;
    bool msrc = mask[src] != 0;

    if (lane < 42) {
        la[wid][lane] = locl[(size_t)src * 42 + lane];
        int b = lane / 3;
        int i = lane - b * 3;
        const float* Rs = rot + (size_t)src * 9;
        const float* ts = trans + (size_t)src * 3;
        const float* ed = eff + (size_t)dst * 42 + b * 3;
        // dst_in_src[b][i] = sum_j Rs[j][i] * (eff_dst[b][j] - ts[j])
        lb[wid][lane] = Rs[0 * 3 + i] * (ed[0] - ts[0]) +
                        Rs[1 * 3 + i] * (ed[1] - ts[1]) +
                        Rs[2 * 3 + i] * (ed[2] - ts[2]);
    }
    __syncthreads();
    if (e >= E) return;

    // edge distance between CA atoms (pre-noising positions)
    float cdx = xca[dst * 3 + 0] - xca[src * 3 + 0];
    float cdy = xca[dst * 3 + 1] - xca[src * 3 + 1];
    float cdz = xca[dst * 3 + 2] - xca[src * 3 + 2];
    float D = sqrtf(cdx * cdx + cdy * cdy + cdz * cdz);
    float dfl = (float)(dst - src);
    int qs = seq[src];
    int qd = seq[dst];

    // unnoised_edges[-1]: scalar from LAST edge (reference quirk)
    int dl = ei[E - 1];
    int sl = ei[2 * E - 1];
    float ul = ((mask[dl] != 0) || (mask[sl] != 0)) ? 0.f : 1.f;

    float* row = out + (size_t)e * FEAT;

    // ---- iteration 0: features [0,256) -- 4 consecutive per lane ----
    {
        int f0 = lane * 4;
        float v[4];
#pragma unroll
        for (int c = 0; c < 4; ++c) {
            int f = f0 + c;
            float r;
            if (f == 0) {
                r = mdst ? 1.f : 0.f;
            } else if (f == 1) {
                r = msrc ? 1.f : 0.f;
            } else if (f < 23) {
                r = (!msrc && qs == (f - 2)) ? 1.f : 0.f;
            } else if (f < 44) {
                r = (!mdst && qd == (f - 23)) ? 1.f : 0.f;
            } else if (f < 108) {
                float mu = (float)(f - 44) * (20.0f / 63.0f);
                float t = (D - mu) * 3.2f;  // sigma = 20/64 -> 1/sigma = 3.2
                r = expf(-t * t);
            } else if (f < 172) {
                int k = f - 108;
                float fr = expf((float)(2 * (k & 31)) * POSC64);
                float ang = dfl * fr;
                r = (k < 32) ? cosf(ang) : sinf(ang);
            } else if (f < 214) {
                r = msrc ? 0.f : la[wid][f - 172];
            } else {
                r = mdst ? 0.f : lb[wid][f - 214];
            }
            v[c] = r;
        }
        float4 o;
        o.x = v[0]; o.y = v[1]; o.z = v[2]; o.w = v[3];
        *reinterpret_cast<float4*>(row + f0) = o;
    }

    // ---- iteration 1: pair block, features [256,452) = 196 = 49 lanes x 4 ----
    if (lane < 49) {
        int p0 = lane * 4;
        float v[4];
#pragma unroll
        for (int c = 0; c < 4; ++c) {
            int p = p0 + c;
            int a = p / 14;
            int b = p - a * 14;
            float d0 = la[wid][a * 3 + 0] - lb[wid][b * 3 + 0] + 1e-8f;
            float d1 = la[wid][a * 3 + 1] - lb[wid][b * 3 + 1] + 1e-8f;
            float d2 = la[wid][a * 3 + 2] - lb[wid][b * 3 + 2] + 1e-8f;
            v[c] = sqrtf(d0 * d0 + d1 * d1 + d2 * d2) * ul;
        }
        float4 o;
        o.x = v[0]; o.y = v[1]; o.z = v[2]; o.w = v[3];
        *reinterpret_cast<float4*>(row + 256 + p0) = o;
    }
}

extern "C" void kernel_launch(void* const* d_in, const int* in_sizes, int n_in,
                              void* d_out, int out_size, void* d_ws, size_t ws_size,
                              hipStream_t stream) {
    const float* atom14 = (const float*)d_in[0];
    const float* rot    = (const float*)d_in[1];
    const float* trans  = (const float*)d_in[2];
    const int*   mask   = (const int*)d_in[3];
    const int*   seq    = (const int*)d_in[4];
    const int*   ei     = (const int*)d_in[5];
    float* out = (float*)d_out;

    int n_nodes = in_sizes[3];
    int E = in_sizes[5] / 2;

    float* ws   = (float*)d_ws;
    float* xca  = ws;                        // n*3
    float* locl = ws + (size_t)n_nodes * 3;  // n*42
    float* eff  = ws + (size_t)n_nodes * 45; // n*42

    int ntot = n_nodes * 14;
    node_kernel<<<(ntot + 255) / 256, 256, 0, stream>>>(
        atom14, rot, trans, mask, xca, locl, eff, n_nodes);

    int nblk = (E + 3) / 4;
    edge_kernel<<<nblk, 256, 0, stream>>>(
        ei, mask, seq, rot, trans, xca, locl, eff, out, E);
}

// Round 3
// 853.781 us; speedup vs baseline: 1.0528x; 1.0528x over previous
//
#include <hip/hip_runtime.h>
#include <math.h>

// ---------------------------------------------------------------------------
// MLMPairwiseAtomicEmbedding
// Feature layout per edge (452 f32):
//   [0]       noised_dst
//   [1]       noised_src
//   [2:23]    one_hot(seq[src],21) * !noised_src
//   [23:44]   one_hot(seq[dst],21) * !noised_dst
//   [44:108]  rbf(|Xca[dst]-Xca[src]|), 64
//   [108:172] pos embed: cos(d*freq[0:32]), sin(d*freq[0:32])
//   [172:214] local[src] (42) * !noised_src
//   [214:256] dst_in_src_local (42) * !noised_dst
//   [256:452] pair norms (14x14) * unnoised_edges[-1]  (scalar! last edge)
// ---------------------------------------------------------------------------

#define SCALE 0.1f
#define FEAT 452
// ln(10000)/64 rounded to f32 (matches JAX's f32 scalar)
#define POSC64 (-0.14391157f)
// 1/(2*pi) split: C_HI = f32 nearest, C_LO = residual
#define INV2PI_HI 0.15915494f
#define INV2PI_LO 6.4206383e-9f

typedef float f32x4 __attribute__((ext_vector_type(4)));

__global__ void node_kernel(const float* __restrict__ atom14,
                            const float* __restrict__ rot,
                            const float* __restrict__ trans,
                            const int* __restrict__ mask,
                            float* __restrict__ xca,
                            float* __restrict__ locl,
                            float* __restrict__ eff,
                            int n_nodes) {
    int idx = blockIdx.x * blockDim.x + threadIdx.x;
    int total = n_nodes * 14;
    if (idx >= total) return;
    int n = idx / 14;
    int a = idx - n * 14;

    const float* R = rot + (size_t)n * 9;
    float tx = trans[n * 3 + 0], ty = trans[n * 3 + 1], tz = trans[n * 3 + 2];
    float px = atom14[(size_t)idx * 3 + 0] * SCALE;
    float py = atom14[(size_t)idx * 3 + 1] * SCALE;
    float pz = atom14[(size_t)idx * 3 + 2] * SCALE;

    if (a == 1) {  // X_ca taken from scaled atoms BEFORE the noising replace
        xca[n * 3 + 0] = px;
        xca[n * 3 + 1] = py;
        xca[n * 3 + 2] = pz;
    }

    float ex = px, ey = py, ez = pz;
    if (mask[n] != 0) {
        if (a < 4) {
            const float BBX[4] = {-0.525f, 0.0f, 1.526f, 2.153f};
            const float BBY[4] = {1.363f, 0.0f, 0.0f, -1.062f};
            float lx = BBX[a], ly = BBY[a];
            ex = R[0] * lx + R[1] * ly + tx;
            ey = R[3] * lx + R[4] * ly + ty;
            ez = R[6] * lx + R[7] * ly + tz;
        } else {
            ex = 0.f; ey = 0.f; ez = 0.f;
        }
    }

    float dx = ex - tx, dy = ey - ty, dz = ez - tz;
    float l0 = R[0] * dx + R[3] * dy + R[6] * dz;
    float l1 = R[1] * dx + R[4] * dy + R[7] * dz;
    float l2 = R[2] * dx + R[5] * dy + R[8] * dz;

    eff[(size_t)idx * 3 + 0] = ex;
    eff[(size_t)idx * 3 + 1] = ey;
    eff[(size_t)idx * 3 + 2] = ez;
    locl[(size_t)idx * 3 + 0] = l0;
    locl[(size_t)idx * 3 + 1] = l1;
    locl[(size_t)idx * 3 + 2] = l2;
}

// cos/sin of `ang` radians via compensated reduction to revolutions + HW trig
__device__ __forceinline__ float fast_cos(float ang) {
    float p = ang * INV2PI_HI;
    float e = __builtin_fmaf(ang, INV2PI_HI, -p);
    e = __builtin_fmaf(ang, INV2PI_LO, e);
    float k = rintf(p);
    float rf = (p - k) + e;
    return __builtin_amdgcn_cosf(rf);
}
__device__ __forceinline__ float fast_sin(float ang) {
    float p = ang * INV2PI_HI;
    float e = __builtin_fmaf(ang, INV2PI_HI, -p);
    e = __builtin_fmaf(ang, INV2PI_LO, e);
    float k = rintf(p);
    float rf = (p - k) + e;
    return __builtin_amdgcn_sinf(rf);
}

__global__ __launch_bounds__(256) void edge_kernel(
    const int* __restrict__ ei,     // [2,E] row0=dst row1=src
    const int* __restrict__ mask,   // [N]
    const int* __restrict__ seq,    // [N]
    const float* __restrict__ rot,  // [N,3,3]
    const float* __restrict__ trans,// [N,3]
    const float* __restrict__ xca,  // [N,3]
    const float* __restrict__ locl, // [N,14,3]
    const float* __restrict__ eff,  // [N,14,3]
    float* __restrict__ out,        // [E,452]
    int E) {
    __shared__ float la[4][42];  // local[src]
    __shared__ float lb[4][42];  // dst atoms in src frame

    int wid = threadIdx.x >> 6;
    int lane = threadIdx.x & 63;
    int e = blockIdx.x * 4 + wid;
    int ec = (e < E) ? e : (E - 1);

    int dst = ei[ec];
    int src = ei[E + ec];
    bool mdst = mask[dst] != 0;
    bool msrc = mask[src] != 0;

    if (lane < 42) {
        la[wid][lane] = locl[(size_t)src * 42 + lane];
        int b = lane / 3;
        int i = lane - b * 3;
        const float* Rs = rot + (size_t)src * 9;
        const float* ts = trans + (size_t)src * 3;
        const float* ed = eff + (size_t)dst * 42 + b * 3;
        lb[wid][lane] = Rs[0 * 3 + i] * (ed[0] - ts[0]) +
                        Rs[1 * 3 + i] * (ed[1] - ts[1]) +
                        Rs[2 * 3 + i] * (ed[2] - ts[2]);
    }
    __syncthreads();
    if (e >= E) return;

    float cdx = xca[dst * 3 + 0] - xca[src * 3 + 0];
    float cdy = xca[dst * 3 + 1] - xca[src * 3 + 1];
    float cdz = xca[dst * 3 + 2] - xca[src * 3 + 2];
    float D = sqrtf(cdx * cdx + cdy * cdy + cdz * cdz);
    float dfl = (float)(dst - src);
    int qs = seq[src];
    int qd = seq[dst];

    // unnoised_edges[-1]: scalar from LAST edge (reference quirk)
    int dl = ei[E - 1];
    int sl = ei[2 * E - 1];
    float ul = ((mask[dl] != 0) || (mask[sl] != 0)) ? 0.f : 1.f;

    float* row = out + (size_t)e * FEAT;

    // ---- features [0,256): region-per-lane, 4 consecutive per lane ----
    int f0 = lane * 4;
    float v0, v1, v2, v3;
    if (lane < 11) {
        // flags + one-hots (f 0..43), cheap int compares
        float v[4];
#pragma unroll
        for (int c = 0; c < 4; ++c) {
            int f = f0 + c;
            float r;
            if (f == 0)       r = mdst ? 1.f : 0.f;
            else if (f == 1)  r = msrc ? 1.f : 0.f;
            else if (f < 23)  r = (!msrc && qs == (f - 2)) ? 1.f : 0.f;
            else              r = (!mdst && qd == (f - 23)) ? 1.f : 0.f;
            v[c] = r;
        }
        v0 = v[0]; v1 = v[1]; v2 = v[2]; v3 = v[3];
    } else if (lane < 27) {
        // RBF (f 44..107)
        float v[4];
        int k0 = f0 - 44;
#pragma unroll
        for (int c = 0; c < 4; ++c) {
            float mu = (float)(k0 + c) * (20.0f / 63.0f);
            float t = (D - mu) * 3.2f;  // 1/sigma = 64/20
            v[c] = __expf(-t * t);
        }
        v0 = v[0]; v1 = v[1]; v2 = v[2]; v3 = v[3];
    } else if (lane < 35) {
        // pos-embed cos (k 0..31)
        float v[4];
        int k0 = f0 - 108;
#pragma unroll
        for (int c = 0; c < 4; ++c) {
            float fr = expf((float)(2 * (k0 + c)) * POSC64);
            v[c] = fast_cos(dfl * fr);
        }
        v0 = v[0]; v1 = v[1]; v2 = v[2]; v3 = v[3];
    } else if (lane < 43) {
        // pos-embed sin (k 32..63 -> freq idx k-32)
        float v[4];
        int k0 = f0 - 140;  // freq index base
#pragma unroll
        for (int c = 0; c < 4; ++c) {
            float fr = expf((float)(2 * (k0 + c)) * POSC64);
            v[c] = fast_sin(dfl * fr);
        }
        v0 = v[0]; v1 = v[1]; v2 = v[2]; v3 = v[3];
    } else {
        // locals (f 172..255); lane 53 straddles the 214 boundary
        float sla = msrc ? 0.f : 1.f;
        float slb = mdst ? 0.f : 1.f;
        float v[4];
#pragma unroll
        for (int c = 0; c < 4; ++c) {
            int f = f0 + c;
            v[c] = (f < 214) ? la[wid][f - 172] * sla
                             : lb[wid][f - 214] * slb;
        }
        v0 = v[0]; v1 = v[1]; v2 = v[2]; v3 = v[3];
    }
    {
        f32x4 o = {v0, v1, v2, v3};
        __builtin_nontemporal_store(o, reinterpret_cast<f32x4*>(row + f0));
    }

    // ---- pair block [256,452): 196 = 49 lanes x 4 ----
    if (lane < 49) {
        int p0 = lane * 4;
        float v[4];
#pragma unroll
        for (int c = 0; c < 4; ++c) {
            int p = p0 + c;
            int a = p / 14;
            int b = p - a * 14;
            float d0 = la[wid][a * 3 + 0] - lb[wid][b * 3 + 0] + 1e-8f;
            float d1 = la[wid][a * 3 + 1] - lb[wid][b * 3 + 1] + 1e-8f;
            float d2 = la[wid][a * 3 + 2] - lb[wid][b * 3 + 2] + 1e-8f;
            v[c] = sqrtf(d0 * d0 + d1 * d1 + d2 * d2) * ul;
        }
        f32x4 o = {v[0], v[1], v[2], v[3]};
        __builtin_nontemporal_store(o, reinterpret_cast<f32x4*>(row + 256 + p0));
    }
}

extern "C" void kernel_launch(void* const* d_in, const int* in_sizes, int n_in,
                              void* d_out, int out_size, void* d_ws, size_t ws_size,
                              hipStream_t stream) {
    const float* atom14 = (const float*)d_in[0];
    const float* rot    = (const float*)d_in[1];
    const float* trans  = (const float*)d_in[2];
    const int*   mask   = (const int*)d_in[3];
    const int*   seq    = (const int*)d_in[4];
    const int*   ei     = (const int*)d_in[5];
    float* out = (float*)d_out;

    int n_nodes = in_sizes[3];
    int E = in_sizes[5] / 2;

    float* ws   = (float*)d_ws;
    float* xca  = ws;                        // n*3
    float* locl = ws + (size_t)n_nodes * 3;  // n*42
    float* eff  = ws + (size_t)n_nodes * 45; // n*42

    int ntot = n_nodes * 14;
    node_kernel<<<(ntot + 255) / 256, 256, 0, stream>>>(
        atom14, rot, trans, mask, xca, locl, eff, n_nodes);

    int nblk = (E + 3) / 4;
    edge_kernel<<<nblk, 256, 0, stream>>>(
        ei, mask, seq, rot, trans, xca, locl, eff, out, E);
}